// Round 1
// baseline (593.712 us; speedup 1.0000x reference)
//
#include <hip/hip_runtime.h>

// MVDR oracle beamformer — MI355X (gfx950)
// Inputs: d_in[0]=mixture (8,2,8,600,257) f32, d_in[1]=target (UNUSED), d_in[2]=noise.
// Output: (8,2,1,600,257) f32.
//
// Phase A: per-(n,f) Hermitian covariance partial sums over t-chunks (no atomics).
// Phase B: reduce chunks, add diagonal loading, invert 8x8 complex (unrolled
//          Gauss-Jordan, no pivot — matrix is diagonally dominant), build W=conj(H).
// Phase C: beamform X = sum_c W[c] * y[c].

constexpr int N_  = 8;
constexpr int C_  = 8;
constexpr int T_  = 600;
constexpr int F_  = 257;
constexpr int TF_  = T_ * F_;       // 154200
constexpr int CTF_ = C_ * TF_;      // 1233600
constexpr int NSTR_ = 2 * CTF_;     // per-batch stride in inputs
constexpr int NF_  = N_ * F_;       // 2056
constexpr int TSPLIT_ = 15;
constexpr int TCHUNK_ = T_ / TSPLIT_;  // 40
constexpr int NPAIR_ = 36;             // lower-triangle pairs of 8x8 Hermitian
constexpr float LOADC_ = 7.0710678118654755e-4f;  // 0.001/sqrt(2)
constexpr float INV_T_ = 1.0f / 600.0f;

struct cx { float r, i; };
__device__ __forceinline__ cx cmul(cx a, cx b) { return {a.r*b.r - a.i*b.i, a.r*b.i + a.i*b.r}; }
__device__ __forceinline__ cx csub(cx a, cx b) { return {a.r - b.r, a.i - b.i}; }
__device__ __forceinline__ cx cconj(cx a) { return {a.r, -a.i}; }
__device__ __forceinline__ cx cinv(cx a) {
    float id = 1.0f / (a.r*a.r + a.i*a.i);
    return {a.r*id, -a.i*id};
}
__device__ __forceinline__ cx cmadd(cx acc, cx a, cx b) {
    acc.r += a.r*b.r - a.i*b.i;
    acc.i += a.r*b.i + a.i*b.r;
    return acc;
}

// ---------------------------------------------------------------------------
// Phase A: partial covariance sums.
// grid (5, N, 2*TSPLIT), block 64. Thread owns one f; z&1 selects source
// (0 = noise -> phi_v, 1 = mixture -> phi_y); z>>1 selects t-chunk.
// Partial layout: part[((m*TSPLIT + chunk)*72 + (2p+ri)) * NF + n*F + f]
// ---------------------------------------------------------------------------
__global__ __launch_bounds__(64, 4) void cov_partial(
        const float* __restrict__ mix, const float* __restrict__ noi,
        float* __restrict__ part) {
    int f = blockIdx.x * 64 + threadIdx.x;
    if (f >= F_) return;
    int n = blockIdx.y;
    int z = blockIdx.z;
    int m = z & 1;
    int chunk = z >> 1;
    const float* src = m ? mix : noi;
    const float* base = src + (size_t)n * NSTR_ + f;
    int t0 = chunk * TCHUNK_;

    float accr[NPAIR_], acci[NPAIR_];
#pragma unroll
    for (int p = 0; p < NPAIR_; ++p) { accr[p] = 0.f; acci[p] = 0.f; }

    for (int t = t0; t < t0 + TCHUNK_; ++t) {
        float re[C_], im[C_];
#pragma unroll
        for (int c = 0; c < C_; ++c) {
            const float* pc = base + c * TF_ + t * F_;
            re[c] = pc[0];
            im[c] = pc[CTF_];
        }
        int p = 0;
#pragma unroll
        for (int c = 0; c < C_; ++c) {
#pragma unroll
            for (int d = 0; d <= c; ++d, ++p) {
                // x[c] * conj(x[d])
                accr[p] += re[c]*re[d] + im[c]*im[d];
                acci[p] += im[c]*re[d] - re[c]*im[d];
            }
        }
    }

    float* out = part + (size_t)((m * TSPLIT_ + chunk) * 72) * NF_ + n * F_ + f;
#pragma unroll
    for (int p = 0; p < NPAIR_; ++p) {
        out[(size_t)(2*p)   * NF_] = accr[p];
        out[(size_t)(2*p+1) * NF_] = acci[p];
    }
}

// ---------------------------------------------------------------------------
// Phase B: reduce partials, invert phi_v, build W = conj(H). One thread per (n,f).
// ---------------------------------------------------------------------------
__global__ __launch_bounds__(64, 1) void solve_w(
        const float* __restrict__ part, float* __restrict__ W) {
    int idx = blockIdx.x * 64 + threadIdx.x;  // idx = n*F + f
    if (idx >= NF_) return;

    float vL[72], yL[72];
#pragma unroll
    for (int q = 0; q < 72; ++q) { vL[q] = 0.f; yL[q] = 0.f; }
    for (int ch = 0; ch < TSPLIT_; ++ch) {
        const float* pv = part + (size_t)(ch * 72) * NF_ + idx;
        const float* py = part + (size_t)((TSPLIT_ + ch) * 72) * NF_ + idx;
#pragma unroll
        for (int q = 0; q < 72; ++q) {
            vL[q] += pv[(size_t)q * NF_];
            yL[q] += py[(size_t)q * NF_];
        }
    }

    // Build M = phi_v/T + LOAD*(1+i)*I (full 8x8 from lower triangle)
    cx M[64];
#pragma unroll
    for (int c = 0; c < 8; ++c) {
#pragma unroll
        for (int d = 0; d <= c; ++d) {
            int p = c*(c+1)/2 + d;
            cx val = { vL[2*p] * INV_T_, vL[2*p+1] * INV_T_ };
            if (d == c) { val.r += LOADC_; val.i += LOADC_; }
            M[c*8 + d] = val;
            if (d < c) M[d*8 + c] = cconj(val);
        }
    }

    // In-place Gauss-Jordan inverse, no pivoting (diagonally dominant).
#pragma unroll
    for (int k = 0; k < 8; ++k) {
        cx p = cinv(M[k*8 + k]);
        M[k*8 + k] = p;
#pragma unroll
        for (int j = 0; j < 8; ++j) {
            if (j != k) M[k*8 + j] = cmul(M[k*8 + j], p);
        }
#pragma unroll
        for (int i = 0; i < 8; ++i) {
            if (i == k) continue;
            cx fkt = M[i*8 + k];
#pragma unroll
            for (int j = 0; j < 8; ++j) {
                if (j != k) M[i*8 + j] = csub(M[i*8 + j], cmul(fkt, M[k*8 + j]));
            }
            cx t = cmul(fkt, p);
            M[i*8 + k] = { -t.r, -t.i };
        }
    }

    // tr = sum_{c,d} A[c][d] * phi_y[d][c];  g0[c] = sum_d A[c][d] * phi_y[d][0]
    cx tr = {0.f, 0.f};
    cx g0[8];
#pragma unroll
    for (int c = 0; c < 8; ++c) g0[c] = (cx){0.f, 0.f};

#pragma unroll
    for (int c = 0; c < 8; ++c) {
#pragma unroll
        for (int d = 0; d < 8; ++d) {
            cx pyv;
            if (d >= c) { int p = d*(d+1)/2 + c; pyv = (cx){ yL[2*p] * INV_T_,  yL[2*p+1] * INV_T_ }; }
            else        { int p = c*(c+1)/2 + d; pyv = (cx){ yL[2*p] * INV_T_, -yL[2*p+1] * INV_T_ }; }
            tr = cmadd(tr, M[c*8 + d], pyv);
            // phi_y[d][0]: pair (d,0) always stored directly
            int p0 = d*(d+1)/2;
            cx py0 = { yL[2*p0] * INV_T_, yL[2*p0+1] * INV_T_ };
            if (d == 0) { /* same as stored */ }
            g0[c] = cmadd(g0[c], M[c*8 + d], py0);
        }
    }

    cx l = { tr.r - 8.0f, tr.i - 8.0f };
    float iden = 1.0f / (l.r*l.r + l.i*l.i);

    float* w = W + (size_t)idx * 16;
#pragma unroll
    for (int c = 0; c < 8; ++c) {
        cx ge = g0[c];
        if (c == 0) ge.r -= 1.0f;
        // W = conj(H) = conj(ge) * l / |l|^2
        w[2*c]     = (ge.r*l.r + ge.i*l.i) * iden;
        w[2*c + 1] = (ge.r*l.i - ge.i*l.r) * iden;
    }
}

// ---------------------------------------------------------------------------
// Phase C: beamform. grid (ceil(TF/256), N), block 256. Thread owns flat j=t*F+f.
// ---------------------------------------------------------------------------
__global__ __launch_bounds__(256) void beamform(
        const float* __restrict__ mix, const float* __restrict__ W,
        float* __restrict__ out) {
    int n = blockIdx.y;
    int j = blockIdx.x * 256 + threadIdx.x;
    if (j >= TF_) return;
    int f = j % F_;

    const float4* w4 = (const float4*)(W + (size_t)(n * F_ + f) * 16);
    float4 q0 = w4[0], q1 = w4[1], q2 = w4[2], q3 = w4[3];
    float wv[16] = { q0.x, q0.y, q0.z, q0.w,
                     q1.x, q1.y, q1.z, q1.w,
                     q2.x, q2.y, q2.z, q2.w,
                     q3.x, q3.y, q3.z, q3.w };

    const float* base = mix + (size_t)n * NSTR_ + j;
    float xr = 0.f, xi = 0.f;
#pragma unroll
    for (int c = 0; c < C_; ++c) {
        float yr = base[(size_t)c * TF_];
        float yi = base[(size_t)c * TF_ + CTF_];
        float wr = wv[2*c], wi = wv[2*c + 1];
        xr += wr*yr - wi*yi;
        xi += wr*yi + wi*yr;
    }
    float* op = out + (size_t)n * (2 * TF_);
    op[j]       = xr;
    op[TF_ + j] = xi;
}

extern "C" void kernel_launch(void* const* d_in, const int* in_sizes, int n_in,
                              void* d_out, int out_size, void* d_ws, size_t ws_size,
                              hipStream_t stream) {
    const float* mix = (const float*)d_in[0];
    // d_in[1] = target, unused by the reference
    const float* noi = (const float*)d_in[2];
    float* part = (float*)d_ws;                               // 2*15*72*2056 floats = 17.8 MB
    float* W    = part + (size_t)2 * TSPLIT_ * 72 * NF_;      // 2056*16 floats

    cov_partial<<<dim3(5, N_, 2 * TSPLIT_), 64, 0, stream>>>(mix, noi, part);
    solve_w<<<dim3((NF_ + 63) / 64), 64, 0, stream>>>(part, W);
    beamform<<<dim3((TF_ + 255) / 256, N_), 256, 0, stream>>>(mix, W, (float*)d_out);
}

// Round 2
// 307.020 us; speedup vs baseline: 1.9338x; 1.9338x over previous
//
#include <hip/hip_runtime.h>

// MVDR oracle beamformer — MI355X (gfx950)
// Phase A: per-(n,f) Hermitian covariance partial sums over t-chunks.
// Phase B1: parallel reduction of the 15 t-chunks (in-place into chunk-0 slot).
// Phase B2: streaming solve — invert phi_v (unpivoted GJ, diag-dominant),
//           build W = conj(H) with no large live arrays besides M.
// Phase C: beamform X = sum_c W[c] * y[c].

constexpr int N_  = 8;
constexpr int C_  = 8;
constexpr int T_  = 600;
constexpr int F_  = 257;
constexpr int TF_  = T_ * F_;       // 154200
constexpr int CTF_ = C_ * TF_;      // 1233600
constexpr int NSTR_ = 2 * CTF_;     // per-batch stride in inputs
constexpr int NF_  = N_ * F_;       // 2056
constexpr int TSPLIT_ = 15;
constexpr int TCHUNK_ = T_ / TSPLIT_;  // 40
constexpr int NPAIR_ = 36;             // lower-triangle pairs of 8x8 Hermitian
constexpr float LOADC_ = 7.0710678118654755e-4f;  // 0.001/sqrt(2)
constexpr float INV_T_ = 1.0f / 600.0f;

struct cx { float r, i; };
__device__ __forceinline__ cx cmul(cx a, cx b) { return {a.r*b.r - a.i*b.i, a.r*b.i + a.i*b.r}; }
__device__ __forceinline__ cx csub(cx a, cx b) { return {a.r - b.r, a.i - b.i}; }
__device__ __forceinline__ cx cconj(cx a) { return {a.r, -a.i}; }
__device__ __forceinline__ cx cinv(cx a) {
    float id = 1.0f / (a.r*a.r + a.i*a.i);
    return {a.r*id, -a.i*id};
}
__device__ __forceinline__ cx cmadd(cx acc, cx a, cx b) {
    acc.r += a.r*b.r - a.i*b.i;
    acc.i += a.r*b.i + a.i*b.r;
    return acc;
}

// ---------------------------------------------------------------------------
// Phase A: partial covariance sums.
// grid (5, N, 2*TSPLIT), block 64. Thread owns one f; z&1 selects source
// (0 = noise -> phi_v, 1 = mixture -> phi_y); z>>1 selects t-chunk.
// Partial layout: part[((m*TSPLIT + chunk)*72 + (2p+ri)) * NF + n*F + f]
// ---------------------------------------------------------------------------
__global__ __launch_bounds__(64, 4) void cov_partial(
        const float* __restrict__ mix, const float* __restrict__ noi,
        float* __restrict__ part) {
    int f = blockIdx.x * 64 + threadIdx.x;
    if (f >= F_) return;
    int n = blockIdx.y;
    int z = blockIdx.z;
    int m = z & 1;
    int chunk = z >> 1;
    const float* src = m ? mix : noi;
    const float* base = src + (size_t)n * NSTR_ + f;
    int t0 = chunk * TCHUNK_;

    float accr[NPAIR_], acci[NPAIR_];
#pragma unroll
    for (int p = 0; p < NPAIR_; ++p) { accr[p] = 0.f; acci[p] = 0.f; }

    for (int t = t0; t < t0 + TCHUNK_; ++t) {
        float re[C_], im[C_];
#pragma unroll
        for (int c = 0; c < C_; ++c) {
            const float* pc = base + c * TF_ + t * F_;
            re[c] = pc[0];
            im[c] = pc[CTF_];
        }
        int p = 0;
#pragma unroll
        for (int c = 0; c < C_; ++c) {
#pragma unroll
            for (int d = 0; d <= c; ++d, ++p) {
                accr[p] += re[c]*re[d] + im[c]*im[d];
                acci[p] += im[c]*re[d] - re[c]*im[d];
            }
        }
    }

    float* out = part + (size_t)((m * TSPLIT_ + chunk) * 72) * NF_ + n * F_ + f;
#pragma unroll
    for (int p = 0; p < NPAIR_; ++p) {
        out[(size_t)(2*p)   * NF_] = accr[p];
        out[(size_t)(2*p+1) * NF_] = acci[p];
    }
}

// ---------------------------------------------------------------------------
// Phase B1: reduce the 15 chunks into the chunk-0 slot. One thread per
// (m, q, idx): 2*72*2056 = 296064 threads. Fully coalesced (idx contiguous).
// ---------------------------------------------------------------------------
__global__ __launch_bounds__(256) void reduce_cov(float* __restrict__ part) {
    int flat = blockIdx.x * 256 + threadIdx.x;
    if (flat >= 2 * 72 * NF_) return;
    int idx = flat % NF_;
    int z = flat / NF_;          // z = m*72 + q
    int m = z / 72;
    int q = z % 72;
    size_t base = (size_t)((m * TSPLIT_) * 72 + q) * NF_ + idx;
    float s = 0.f;
#pragma unroll
    for (int ch = 0; ch < TSPLIT_; ++ch) {
        s += part[base + (size_t)(ch * 72) * NF_];
    }
    part[base] = s;   // chunk-0 slot; this thread read it first, safe
}

// ---------------------------------------------------------------------------
// Phase B2: streaming solve. One thread per (n,f). Reads the reduced
// covariances (72 floats each for v and y), builds W = conj(H).
// ---------------------------------------------------------------------------
__global__ __launch_bounds__(64, 1) void solve_w(
        const float* __restrict__ part, float* __restrict__ W) {
    int idx = blockIdx.x * 64 + threadIdx.x;  // idx = n*F + f
    if (idx >= NF_) return;

    const float* pv = part + idx;                                   // m=0, chunk 0
    const float* py = part + (size_t)(TSPLIT_ * 72) * NF_ + idx;    // m=1, chunk 0

    // Build M = phi_v/T + LOAD*(1+i)*I directly from loads.
    cx M[64];
#pragma unroll
    for (int c = 0; c < 8; ++c) {
#pragma unroll
        for (int d = 0; d <= c; ++d) {
            int p = c*(c+1)/2 + d;
            cx val = { pv[(size_t)(2*p) * NF_] * INV_T_,
                       pv[(size_t)(2*p+1) * NF_] * INV_T_ };
            if (d == c) { val.r += LOADC_; val.i += LOADC_; }
            M[c*8 + d] = val;
            if (d < c) M[d*8 + c] = cconj(val);
        }
    }

    // In-place Gauss-Jordan inverse, no pivoting (diagonally dominant).
#pragma unroll
    for (int k = 0; k < 8; ++k) {
        cx p = cinv(M[k*8 + k]);
        M[k*8 + k] = p;
#pragma unroll
        for (int j = 0; j < 8; ++j) {
            if (j != k) M[k*8 + j] = cmul(M[k*8 + j], p);
        }
#pragma unroll
        for (int i = 0; i < 8; ++i) {
            if (i == k) continue;
            cx fkt = M[i*8 + k];
#pragma unroll
            for (int j = 0; j < 8; ++j) {
                if (j != k) M[i*8 + j] = csub(M[i*8 + j], cmul(fkt, M[k*8 + j]));
            }
            cx t = cmul(fkt, p);
            M[i*8 + k] = { -t.r, -t.i };
        }
    }

    // Stream the 36 stored y-pairs: yv = phi_y[a][b] (a >= b), scaled by 1/T.
    //   tr += A[b][a]*yv;  if (a != b) tr += A[a][b]*conj(yv)
    //   if (b == 0): g0[i] += A[i][a]*yv  for all i
    cx tr = {0.f, 0.f};
    cx g0[8];
#pragma unroll
    for (int c = 0; c < 8; ++c) g0[c] = (cx){0.f, 0.f};

#pragma unroll
    for (int a = 0; a < 8; ++a) {
#pragma unroll
        for (int b = 0; b <= a; ++b) {
            int p = a*(a+1)/2 + b;
            cx yv = { py[(size_t)(2*p) * NF_] * INV_T_,
                      py[(size_t)(2*p+1) * NF_] * INV_T_ };
            tr = cmadd(tr, M[b*8 + a], yv);
            if (a != b) tr = cmadd(tr, M[a*8 + b], cconj(yv));
            if (b == 0) {
#pragma unroll
                for (int i = 0; i < 8; ++i) g0[i] = cmadd(g0[i], M[i*8 + a], yv);
            }
        }
    }

    cx l = { tr.r - 8.0f, tr.i - 8.0f };
    float iden = 1.0f / (l.r*l.r + l.i*l.i);

    float* w = W + (size_t)idx * 16;
#pragma unroll
    for (int c = 0; c < 8; ++c) {
        cx ge = g0[c];
        if (c == 0) ge.r -= 1.0f;
        // W = conj(H) = conj(ge) * l / |l|^2
        w[2*c]     = (ge.r*l.r + ge.i*l.i) * iden;
        w[2*c + 1] = (ge.r*l.i - ge.i*l.r) * iden;
    }
}

// ---------------------------------------------------------------------------
// Phase C: beamform. grid (ceil(TF/256), N), block 256. Thread owns flat j=t*F+f.
// ---------------------------------------------------------------------------
__global__ __launch_bounds__(256) void beamform(
        const float* __restrict__ mix, const float* __restrict__ W,
        float* __restrict__ out) {
    int n = blockIdx.y;
    int j = blockIdx.x * 256 + threadIdx.x;
    if (j >= TF_) return;
    int f = j % F_;

    const float4* w4 = (const float4*)(W + (size_t)(n * F_ + f) * 16);
    float4 q0 = w4[0], q1 = w4[1], q2 = w4[2], q3 = w4[3];
    float wv[16] = { q0.x, q0.y, q0.z, q0.w,
                     q1.x, q1.y, q1.z, q1.w,
                     q2.x, q2.y, q2.z, q2.w,
                     q3.x, q3.y, q3.z, q3.w };

    const float* base = mix + (size_t)n * NSTR_ + j;
    float xr = 0.f, xi = 0.f;
#pragma unroll
    for (int c = 0; c < C_; ++c) {
        float yr = base[(size_t)c * TF_];
        float yi = base[(size_t)c * TF_ + CTF_];
        float wr = wv[2*c], wi = wv[2*c + 1];
        xr += wr*yr - wi*yi;
        xi += wr*yi + wi*yr;
    }
    float* op = out + (size_t)n * (2 * TF_);
    op[j]       = xr;
    op[TF_ + j] = xi;
}

extern "C" void kernel_launch(void* const* d_in, const int* in_sizes, int n_in,
                              void* d_out, int out_size, void* d_ws, size_t ws_size,
                              hipStream_t stream) {
    const float* mix = (const float*)d_in[0];
    // d_in[1] = target, unused by the reference
    const float* noi = (const float*)d_in[2];
    float* part = (float*)d_ws;                               // 2*15*72*2056 floats = 17.8 MB
    float* W    = part + (size_t)2 * TSPLIT_ * 72 * NF_;      // 2056*16 floats

    cov_partial<<<dim3(5, N_, 2 * TSPLIT_), 64, 0, stream>>>(mix, noi, part);
    reduce_cov<<<dim3((2 * 72 * NF_ + 255) / 256), 256, 0, stream>>>(part);
    solve_w<<<dim3((NF_ + 63) / 64), 64, 0, stream>>>(part, W);
    beamform<<<dim3((TF_ + 255) / 256, N_), 256, 0, stream>>>(mix, W, (float*)d_out);
}

// Round 3
// 289.137 us; speedup vs baseline: 2.0534x; 1.0619x over previous
//
#include <hip/hip_runtime.h>

// MVDR oracle beamformer — MI355X (gfx950)
// Phase A: per-(n,f) Hermitian covariance partial sums over t-chunks,
//          software-pipelined (double-buffered t-loop), TSPLIT chosen from ws_size.
// Phase B1: parallel reduction of the t-chunks (in-place into chunk-0 slot).
// Phase B2: streaming solve — invert phi_v (unpivoted GJ, diag-dominant),
//           build W = conj(H).
// Phase C: beamform X = sum_c W[c] * y[c].

constexpr int N_  = 8;
constexpr int C_  = 8;
constexpr int T_  = 600;
constexpr int F_  = 257;
constexpr int TF_  = T_ * F_;       // 154200
constexpr int CTF_ = C_ * TF_;      // 1233600
constexpr int NSTR_ = 2 * CTF_;     // per-batch stride in inputs
constexpr int NF_  = N_ * F_;       // 2056
constexpr int NPAIR_ = 36;          // lower-triangle pairs of 8x8 Hermitian
constexpr float LOADC_ = 7.0710678118654755e-4f;  // 0.001/sqrt(2)
constexpr float INV_T_ = 1.0f / 600.0f;

struct cx { float r, i; };
__device__ __forceinline__ cx cmul(cx a, cx b) { return {a.r*b.r - a.i*b.i, a.r*b.i + a.i*b.r}; }
__device__ __forceinline__ cx csub(cx a, cx b) { return {a.r - b.r, a.i - b.i}; }
__device__ __forceinline__ cx cconj(cx a) { return {a.r, -a.i}; }
__device__ __forceinline__ cx cinv(cx a) {
    float id = 1.0f / (a.r*a.r + a.i*a.i);
    return {a.r*id, -a.i*id};
}
__device__ __forceinline__ cx cmadd(cx acc, cx a, cx b) {
    acc.r += a.r*b.r - a.i*b.i;
    acc.i += a.r*b.i + a.i*b.r;
    return acc;
}

// ---------------------------------------------------------------------------
// Phase A: partial covariance sums, double-buffered over t.
// grid (5, N, 2*TSPLIT), block 64. Thread owns one f; z&1 selects source
// (0 = noise -> phi_v, 1 = mixture -> phi_y); z>>1 selects t-chunk.
// Partial layout: part[((m*TSPLIT + chunk)*72 + (2p+ri)) * NF + n*F + f]
// ---------------------------------------------------------------------------
template<int TSPLIT>
__global__ __launch_bounds__(64) void cov_partial(
        const float* __restrict__ mix, const float* __restrict__ noi,
        float* __restrict__ part) {
    constexpr int TCHUNK = T_ / TSPLIT;
    int f = blockIdx.x * 64 + threadIdx.x;
    if (f >= F_) return;
    int n = blockIdx.y;
    int z = blockIdx.z;
    int m = z & 1;
    int chunk = z >> 1;
    const float* src = m ? mix : noi;
    const float* base = src + (size_t)n * NSTR_ + f;
    const float* pt = base + (size_t)(chunk * TCHUNK) * F_;

    float accr[NPAIR_], acci[NPAIR_];
#pragma unroll
    for (int p = 0; p < NPAIR_; ++p) { accr[p] = 0.f; acci[p] = 0.f; }

    float reA[C_], imA[C_];
#pragma unroll
    for (int c = 0; c < C_; ++c) {
        reA[c] = pt[(size_t)c * TF_];
        imA[c] = pt[(size_t)c * TF_ + CTF_];
    }

    for (int tt = 1; tt < TCHUNK; ++tt) {
        float reB[C_], imB[C_];
        const float* pn = pt + (size_t)tt * F_;
#pragma unroll
        for (int c = 0; c < C_; ++c) {
            reB[c] = pn[(size_t)c * TF_];
            imB[c] = pn[(size_t)c * TF_ + CTF_];
        }
        int p = 0;
#pragma unroll
        for (int c = 0; c < C_; ++c) {
#pragma unroll
            for (int d = 0; d <= c; ++d, ++p) {
                accr[p] += reA[c]*reA[d] + imA[c]*imA[d];
                acci[p] += imA[c]*reA[d] - reA[c]*imA[d];
            }
        }
#pragma unroll
        for (int c = 0; c < C_; ++c) { reA[c] = reB[c]; imA[c] = imB[c]; }
    }
    {   // final t
        int p = 0;
#pragma unroll
        for (int c = 0; c < C_; ++c) {
#pragma unroll
            for (int d = 0; d <= c; ++d, ++p) {
                accr[p] += reA[c]*reA[d] + imA[c]*imA[d];
                acci[p] += imA[c]*reA[d] - reA[c]*imA[d];
            }
        }
    }

    float* out = part + (size_t)((m * TSPLIT + chunk) * 72) * NF_ + n * F_ + f;
#pragma unroll
    for (int p = 0; p < NPAIR_; ++p) {
        out[(size_t)(2*p)   * NF_] = accr[p];
        out[(size_t)(2*p+1) * NF_] = acci[p];
    }
}

// ---------------------------------------------------------------------------
// Phase B1: reduce the chunks into the chunk-0 slot. One thread per
// (m, q, idx): 2*72*2056 = 296064 threads. Fully coalesced (idx contiguous).
// ---------------------------------------------------------------------------
__global__ __launch_bounds__(256) void reduce_cov(float* __restrict__ part, int tsplit) {
    int flat = blockIdx.x * 256 + threadIdx.x;
    if (flat >= 2 * 72 * NF_) return;
    int idx = flat % NF_;
    int z = flat / NF_;          // z = m*72 + q
    int m = z / 72;
    int q = z % 72;
    size_t base = (size_t)((m * tsplit) * 72 + q) * NF_ + idx;
    float s = 0.f;
    for (int ch = 0; ch < tsplit; ++ch) {
        s += part[base + (size_t)(ch * 72) * NF_];
    }
    part[base] = s;   // chunk-0 slot; this thread read it first, safe
}

// ---------------------------------------------------------------------------
// Phase B2: streaming solve. One thread per (n,f). yBase = tsplit*72*NF_.
// ---------------------------------------------------------------------------
__global__ __launch_bounds__(64, 1) void solve_w(
        const float* __restrict__ part, float* __restrict__ W, size_t yBase) {
    int idx = blockIdx.x * 64 + threadIdx.x;  // idx = n*F + f
    if (idx >= NF_) return;

    const float* pv = part + idx;            // m=0, chunk 0
    const float* py = part + yBase + idx;    // m=1, chunk 0

    // Build M = phi_v/T + LOAD*(1+i)*I directly from loads.
    cx M[64];
#pragma unroll
    for (int c = 0; c < 8; ++c) {
#pragma unroll
        for (int d = 0; d <= c; ++d) {
            int p = c*(c+1)/2 + d;
            cx val = { pv[(size_t)(2*p) * NF_] * INV_T_,
                       pv[(size_t)(2*p+1) * NF_] * INV_T_ };
            if (d == c) { val.r += LOADC_; val.i += LOADC_; }
            M[c*8 + d] = val;
            if (d < c) M[d*8 + c] = cconj(val);
        }
    }

    // In-place Gauss-Jordan inverse, no pivoting (diagonally dominant).
#pragma unroll
    for (int k = 0; k < 8; ++k) {
        cx p = cinv(M[k*8 + k]);
        M[k*8 + k] = p;
#pragma unroll
        for (int j = 0; j < 8; ++j) {
            if (j != k) M[k*8 + j] = cmul(M[k*8 + j], p);
        }
#pragma unroll
        for (int i = 0; i < 8; ++i) {
            if (i == k) continue;
            cx fkt = M[i*8 + k];
#pragma unroll
            for (int j = 0; j < 8; ++j) {
                if (j != k) M[i*8 + j] = csub(M[i*8 + j], cmul(fkt, M[k*8 + j]));
            }
            cx t = cmul(fkt, p);
            M[i*8 + k] = { -t.r, -t.i };
        }
    }

    // Stream the 36 stored y-pairs: yv = phi_y[a][b] (a >= b), scaled by 1/T.
    cx tr = {0.f, 0.f};
    cx g0[8];
#pragma unroll
    for (int c = 0; c < 8; ++c) g0[c] = (cx){0.f, 0.f};

#pragma unroll
    for (int a = 0; a < 8; ++a) {
#pragma unroll
        for (int b = 0; b <= a; ++b) {
            int p = a*(a+1)/2 + b;
            cx yv = { py[(size_t)(2*p) * NF_] * INV_T_,
                      py[(size_t)(2*p+1) * NF_] * INV_T_ };
            tr = cmadd(tr, M[b*8 + a], yv);
            if (a != b) tr = cmadd(tr, M[a*8 + b], cconj(yv));
            if (b == 0) {
#pragma unroll
                for (int i = 0; i < 8; ++i) g0[i] = cmadd(g0[i], M[i*8 + a], yv);
            }
        }
    }

    cx l = { tr.r - 8.0f, tr.i - 8.0f };
    float iden = 1.0f / (l.r*l.r + l.i*l.i);

    float* w = W + (size_t)idx * 16;
#pragma unroll
    for (int c = 0; c < 8; ++c) {
        cx ge = g0[c];
        if (c == 0) ge.r -= 1.0f;
        // W = conj(H) = conj(ge) * l / |l|^2
        w[2*c]     = (ge.r*l.r + ge.i*l.i) * iden;
        w[2*c + 1] = (ge.r*l.i - ge.i*l.r) * iden;
    }
}

// ---------------------------------------------------------------------------
// Phase C: beamform. grid (ceil(TF/256), N), block 256. Thread owns flat j=t*F+f.
// ---------------------------------------------------------------------------
__global__ __launch_bounds__(256) void beamform(
        const float* __restrict__ mix, const float* __restrict__ W,
        float* __restrict__ out) {
    int n = blockIdx.y;
    int j = blockIdx.x * 256 + threadIdx.x;
    if (j >= TF_) return;
    int f = j % F_;

    const float4* w4 = (const float4*)(W + (size_t)(n * F_ + f) * 16);
    float4 q0 = w4[0], q1 = w4[1], q2 = w4[2], q3 = w4[3];
    float wv[16] = { q0.x, q0.y, q0.z, q0.w,
                     q1.x, q1.y, q1.z, q1.w,
                     q2.x, q2.y, q2.z, q2.w,
                     q3.x, q3.y, q3.z, q3.w };

    const float* base = mix + (size_t)n * NSTR_ + j;
    float xr = 0.f, xi = 0.f;
#pragma unroll
    for (int c = 0; c < C_; ++c) {
        float yr = base[(size_t)c * TF_];
        float yi = base[(size_t)c * TF_ + CTF_];
        float wr = wv[2*c], wi = wv[2*c + 1];
        xr += wr*yr - wi*yi;
        xi += wr*yi + wi*yr;
    }
    float* op = out + (size_t)n * (2 * TF_);
    op[j]       = xr;
    op[TF_ + j] = xi;
}

extern "C" void kernel_launch(void* const* d_in, const int* in_sizes, int n_in,
                              void* d_out, int out_size, void* d_ws, size_t ws_size,
                              hipStream_t stream) {
    const float* mix = (const float*)d_in[0];
    // d_in[1] = target, unused by the reference
    const float* noi = (const float*)d_in[2];

    // TSPLIT=40 needs 2*40*72*NF + 16*NF floats of scratch (~47.5 MB).
    const size_t need40 = ((size_t)2 * 40 * 72 * NF_ + (size_t)16 * NF_) * 4;
    float* part = (float*)d_ws;
    int tsplit;
    if (ws_size >= need40) {
        tsplit = 40;
        cov_partial<40><<<dim3(5, N_, 2 * 40), 64, 0, stream>>>(mix, noi, part);
    } else {
        tsplit = 15;
        cov_partial<15><<<dim3(5, N_, 2 * 15), 64, 0, stream>>>(mix, noi, part);
    }
    float* W = part + (size_t)2 * tsplit * 72 * NF_;

    reduce_cov<<<dim3((2 * 72 * NF_ + 255) / 256), 256, 0, stream>>>(part, tsplit);
    solve_w<<<dim3((NF_ + 63) / 64), 64, 0, stream>>>(part, W, (size_t)tsplit * 72 * NF_);
    beamform<<<dim3((TF_ + 255) / 256, N_), 256, 0, stream>>>(mix, W, (float*)d_out);
}

// Round 4
// 284.704 us; speedup vs baseline: 2.0854x; 1.0156x over previous
//
#include <hip/hip_runtime.h>

// MVDR oracle beamformer — MI355X (gfx950)
// Phase A: per-(n,f) Hermitian covariance partial sums over t-chunks,
//          double-buffered t-loop. __launch_bounds__(64,1): the live set is
//          ~116 VGPRs (72 acc + 32 load buf + addr) — default heuristic capped
//          at 68 VGPR and spilled to scratch (R3: VALUBusy 16%, 1.9 TB/s).
// Phase B1: float4 parallel reduction of the t-chunks (into chunk-0 slot).
// Phase B2: streaming solve — invert phi_v (unpivoted GJ, diag-dominant),
//           build W = conj(H).
// Phase C: beamform X = sum_c W[c] * y[c].

constexpr int N_  = 8;
constexpr int C_  = 8;
constexpr int T_  = 600;
constexpr int F_  = 257;
constexpr int TF_  = T_ * F_;       // 154200
constexpr int CTF_ = C_ * TF_;      // 1233600
constexpr int NSTR_ = 2 * CTF_;     // per-batch stride in inputs
constexpr int NF_  = N_ * F_;       // 2056
constexpr int NPAIR_ = 36;          // lower-triangle pairs of 8x8 Hermitian
constexpr float LOADC_ = 7.0710678118654755e-4f;  // 0.001/sqrt(2)
constexpr float INV_T_ = 1.0f / 600.0f;

struct cx { float r, i; };
__device__ __forceinline__ cx cmul(cx a, cx b) { return {a.r*b.r - a.i*b.i, a.r*b.i + a.i*b.r}; }
__device__ __forceinline__ cx csub(cx a, cx b) { return {a.r - b.r, a.i - b.i}; }
__device__ __forceinline__ cx cconj(cx a) { return {a.r, -a.i}; }
__device__ __forceinline__ cx cinv(cx a) {
    float id = 1.0f / (a.r*a.r + a.i*a.i);
    return {a.r*id, -a.i*id};
}
__device__ __forceinline__ cx cmadd(cx acc, cx a, cx b) {
    acc.r += a.r*b.r - a.i*b.i;
    acc.i += a.r*b.i + a.i*b.r;
    return acc;
}

// ---------------------------------------------------------------------------
// Phase A: partial covariance sums, double-buffered over t.
// grid (5, N, 2*TSPLIT), block 64. Thread owns one f; z&1 selects source
// (0 = noise -> phi_v, 1 = mixture -> phi_y); z>>1 selects t-chunk.
// Partial layout: part[((m*TSPLIT + chunk)*72 + (2p+ri)) * NF + n*F + f]
// ---------------------------------------------------------------------------
template<int TSPLIT>
__global__ __launch_bounds__(64, 1) void cov_partial(
        const float* __restrict__ mix, const float* __restrict__ noi,
        float* __restrict__ part) {
    constexpr int TCHUNK = T_ / TSPLIT;
    int f = blockIdx.x * 64 + threadIdx.x;
    if (f >= F_) return;
    int n = blockIdx.y;
    int z = blockIdx.z;
    int m = z & 1;
    int chunk = z >> 1;
    const float* src = m ? mix : noi;
    const float* base = src + (size_t)n * NSTR_ + f;
    const float* pt = base + (size_t)(chunk * TCHUNK) * F_;

    float accr[NPAIR_], acci[NPAIR_];
#pragma unroll
    for (int p = 0; p < NPAIR_; ++p) { accr[p] = 0.f; acci[p] = 0.f; }

    float reA[C_], imA[C_];
#pragma unroll
    for (int c = 0; c < C_; ++c) {
        reA[c] = pt[(size_t)c * TF_];
        imA[c] = pt[(size_t)c * TF_ + CTF_];
    }

#pragma unroll 3
    for (int tt = 1; tt < TCHUNK; ++tt) {
        float reB[C_], imB[C_];
        const float* pn = pt + (size_t)tt * F_;
#pragma unroll
        for (int c = 0; c < C_; ++c) {
            reB[c] = pn[(size_t)c * TF_];
            imB[c] = pn[(size_t)c * TF_ + CTF_];
        }
        int p = 0;
#pragma unroll
        for (int c = 0; c < C_; ++c) {
#pragma unroll
            for (int d = 0; d <= c; ++d, ++p) {
                accr[p] += reA[c]*reA[d] + imA[c]*imA[d];
                acci[p] += imA[c]*reA[d] - reA[c]*imA[d];
            }
        }
#pragma unroll
        for (int c = 0; c < C_; ++c) { reA[c] = reB[c]; imA[c] = imB[c]; }
    }
    {   // final t
        int p = 0;
#pragma unroll
        for (int c = 0; c < C_; ++c) {
#pragma unroll
            for (int d = 0; d <= c; ++d, ++p) {
                accr[p] += reA[c]*reA[d] + imA[c]*imA[d];
                acci[p] += imA[c]*reA[d] - reA[c]*imA[d];
            }
        }
    }

    float* out = part + (size_t)((m * TSPLIT + chunk) * 72) * NF_ + n * F_ + f;
#pragma unroll
    for (int p = 0; p < NPAIR_; ++p) {
        out[(size_t)(2*p)   * NF_] = accr[p];
        out[(size_t)(2*p+1) * NF_] = acci[p];
    }
}

// ---------------------------------------------------------------------------
// Phase B1: reduce the chunks into the chunk-0 slot, float4-vectorized.
// One thread per (m, q, idx4): 2*72*514 = 74016 threads. All strides are
// multiples of NF_ floats = 8224 B (16B-aligned), idx4*16 B aligned.
// ---------------------------------------------------------------------------
__global__ __launch_bounds__(256) void reduce_cov(float* __restrict__ part, int tsplit) {
    int flat = blockIdx.x * 256 + threadIdx.x;
    constexpr int NQ4 = NF_ / 4;   // 514
    if (flat >= 2 * 72 * NQ4) return;
    int idx4 = flat % NQ4;
    int z = flat / NQ4;          // z = m*72 + q
    int m = z / 72;
    int q = z % 72;
    const float4* p4 = (const float4*)(part) + ((size_t)((m * tsplit) * 72 + q) * NF_) / 4 + idx4;
    float4 s = {0.f, 0.f, 0.f, 0.f};
    for (int ch = 0; ch < tsplit; ++ch) {
        float4 v = p4[(size_t)(ch * 72) * NF_ / 4];
        s.x += v.x; s.y += v.y; s.z += v.z; s.w += v.w;
    }
    *(float4*)((float*)part + (size_t)((m * tsplit) * 72 + q) * NF_ + idx4 * 4) = s;
}

// ---------------------------------------------------------------------------
// Phase B2: streaming solve. One thread per (n,f). yBase = tsplit*72*NF_.
// ---------------------------------------------------------------------------
__global__ __launch_bounds__(64, 1) void solve_w(
        const float* __restrict__ part, float* __restrict__ W, size_t yBase) {
    int idx = blockIdx.x * 64 + threadIdx.x;  // idx = n*F + f
    if (idx >= NF_) return;

    const float* pv = part + idx;            // m=0, chunk 0
    const float* py = part + yBase + idx;    // m=1, chunk 0

    // Build M = phi_v/T + LOAD*(1+i)*I directly from loads.
    cx M[64];
#pragma unroll
    for (int c = 0; c < 8; ++c) {
#pragma unroll
        for (int d = 0; d <= c; ++d) {
            int p = c*(c+1)/2 + d;
            cx val = { pv[(size_t)(2*p) * NF_] * INV_T_,
                       pv[(size_t)(2*p+1) * NF_] * INV_T_ };
            if (d == c) { val.r += LOADC_; val.i += LOADC_; }
            M[c*8 + d] = val;
            if (d < c) M[d*8 + c] = cconj(val);
        }
    }

    // In-place Gauss-Jordan inverse, no pivoting (diagonally dominant).
#pragma unroll
    for (int k = 0; k < 8; ++k) {
        cx p = cinv(M[k*8 + k]);
        M[k*8 + k] = p;
#pragma unroll
        for (int j = 0; j < 8; ++j) {
            if (j != k) M[k*8 + j] = cmul(M[k*8 + j], p);
        }
#pragma unroll
        for (int i = 0; i < 8; ++i) {
            if (i == k) continue;
            cx fkt = M[i*8 + k];
#pragma unroll
            for (int j = 0; j < 8; ++j) {
                if (j != k) M[i*8 + j] = csub(M[i*8 + j], cmul(fkt, M[k*8 + j]));
            }
            cx t = cmul(fkt, p);
            M[i*8 + k] = { -t.r, -t.i };
        }
    }

    // Stream the 36 stored y-pairs: yv = phi_y[a][b] (a >= b), scaled by 1/T.
    cx tr = {0.f, 0.f};
    cx g0[8];
#pragma unroll
    for (int c = 0; c < 8; ++c) g0[c] = (cx){0.f, 0.f};

#pragma unroll
    for (int a = 0; a < 8; ++a) {
#pragma unroll
        for (int b = 0; b <= a; ++b) {
            int p = a*(a+1)/2 + b;
            cx yv = { py[(size_t)(2*p) * NF_] * INV_T_,
                      py[(size_t)(2*p+1) * NF_] * INV_T_ };
            tr = cmadd(tr, M[b*8 + a], yv);
            if (a != b) tr = cmadd(tr, M[a*8 + b], cconj(yv));
            if (b == 0) {
#pragma unroll
                for (int i = 0; i < 8; ++i) g0[i] = cmadd(g0[i], M[i*8 + a], yv);
            }
        }
    }

    cx l = { tr.r - 8.0f, tr.i - 8.0f };
    float iden = 1.0f / (l.r*l.r + l.i*l.i);

    float* w = W + (size_t)idx * 16;
#pragma unroll
    for (int c = 0; c < 8; ++c) {
        cx ge = g0[c];
        if (c == 0) ge.r -= 1.0f;
        // W = conj(H) = conj(ge) * l / |l|^2
        w[2*c]     = (ge.r*l.r + ge.i*l.i) * iden;
        w[2*c + 1] = (ge.r*l.i - ge.i*l.r) * iden;
    }
}

// ---------------------------------------------------------------------------
// Phase C: beamform. grid (ceil(TF/256), N), block 256. Thread owns flat j=t*F+f.
// ---------------------------------------------------------------------------
__global__ __launch_bounds__(256) void beamform(
        const float* __restrict__ mix, const float* __restrict__ W,
        float* __restrict__ out) {
    int n = blockIdx.y;
    int j = blockIdx.x * 256 + threadIdx.x;
    if (j >= TF_) return;
    int f = j % F_;

    const float4* w4 = (const float4*)(W + (size_t)(n * F_ + f) * 16);
    float4 q0 = w4[0], q1 = w4[1], q2 = w4[2], q3 = w4[3];
    float wv[16] = { q0.x, q0.y, q0.z, q0.w,
                     q1.x, q1.y, q1.z, q1.w,
                     q2.x, q2.y, q2.z, q2.w,
                     q3.x, q3.y, q3.z, q3.w };

    const float* base = mix + (size_t)n * NSTR_ + j;
    float xr = 0.f, xi = 0.f;
#pragma unroll
    for (int c = 0; c < C_; ++c) {
        float yr = base[(size_t)c * TF_];
        float yi = base[(size_t)c * TF_ + CTF_];
        float wr = wv[2*c], wi = wv[2*c + 1];
        xr += wr*yr - wi*yi;
        xi += wr*yi + wi*yr;
    }
    float* op = out + (size_t)n * (2 * TF_);
    op[j]       = xr;
    op[TF_ + j] = xi;
}

extern "C" void kernel_launch(void* const* d_in, const int* in_sizes, int n_in,
                              void* d_out, int out_size, void* d_ws, size_t ws_size,
                              hipStream_t stream) {
    const float* mix = (const float*)d_in[0];
    // d_in[1] = target, unused by the reference
    const float* noi = (const float*)d_in[2];

    // TSPLIT=40 needs 2*40*72*NF + 16*NF floats of scratch (~47.5 MB).
    const size_t need40 = ((size_t)2 * 40 * 72 * NF_ + (size_t)16 * NF_) * 4;
    float* part = (float*)d_ws;
    int tsplit;
    if (ws_size >= need40) {
        tsplit = 40;
        cov_partial<40><<<dim3(5, N_, 2 * 40), 64, 0, stream>>>(mix, noi, part);
    } else {
        tsplit = 15;
        cov_partial<15><<<dim3(5, N_, 2 * 15), 64, 0, stream>>>(mix, noi, part);
    }
    float* W = part + (size_t)2 * tsplit * 72 * NF_;

    reduce_cov<<<dim3((2 * 72 * (NF_ / 4) + 255) / 256), 256, 0, stream>>>(part, tsplit);
    solve_w<<<dim3((NF_ + 63) / 64), 64, 0, stream>>>(part, W, (size_t)tsplit * 72 * NF_);
    beamform<<<dim3((TF_ + 255) / 256, N_), 256, 0, stream>>>(mix, W, (float*)d_out);
}

// Round 5
// 274.493 us; speedup vs baseline: 2.1629x; 1.0372x over previous
//
#include <hip/hip_runtime.h>

// MVDR oracle beamformer — MI355X (gfx950)
// Phase A: per-(n,f) Hermitian covariance partial sums over t-chunks,
//          software-pipelined PIPE=4 deep (64 loads / 16 KB in flight per
//          wave) — R4 showed dbuf-1 was latency-bound (VALUBusy 14%, 2 TB/s).
// Phase B1: float4 parallel reduction of the t-chunks (into chunk-0 slot).
// Phase B2: streaming solve — invert phi_v (unpivoted GJ, diag-dominant),
//           build W = conj(H).
// Phase C: beamform X = sum_c W[c] * y[c].

constexpr int N_  = 8;
constexpr int C_  = 8;
constexpr int T_  = 600;
constexpr int F_  = 257;
constexpr int TF_  = T_ * F_;       // 154200
constexpr int CTF_ = C_ * TF_;      // 1233600
constexpr int NSTR_ = 2 * CTF_;     // per-batch stride in inputs
constexpr int NF_  = N_ * F_;       // 2056
constexpr int NPAIR_ = 36;          // lower-triangle pairs of 8x8 Hermitian
constexpr float LOADC_ = 7.0710678118654755e-4f;  // 0.001/sqrt(2)
constexpr float INV_T_ = 1.0f / 600.0f;

struct cx { float r, i; };
__device__ __forceinline__ cx cmul(cx a, cx b) { return {a.r*b.r - a.i*b.i, a.r*b.i + a.i*b.r}; }
__device__ __forceinline__ cx csub(cx a, cx b) { return {a.r - b.r, a.i - b.i}; }
__device__ __forceinline__ cx cconj(cx a) { return {a.r, -a.i}; }
__device__ __forceinline__ cx cinv(cx a) {
    float id = 1.0f / (a.r*a.r + a.i*a.i);
    return {a.r*id, -a.i*id};
}
__device__ __forceinline__ cx cmadd(cx acc, cx a, cx b) {
    acc.r += a.r*b.r - a.i*b.i;
    acc.i += a.r*b.i + a.i*b.r;
    return acc;
}

// ---------------------------------------------------------------------------
// Phase A: partial covariance sums, PIPE-deep software pipeline over t.
// grid (5, N, 2*TSPLIT), block 64 (1 wave). Thread owns one f; z&1 selects
// source (0 = noise -> phi_v, 1 = mixture -> phi_y); z>>1 selects t-chunk.
// Partial layout: part[((m*TSPLIT + chunk)*72 + (2p+ri)) * NF + n*F + f]
// ---------------------------------------------------------------------------
template<int TSPLIT>
__global__ __launch_bounds__(64, 1) void cov_partial(
        const float* __restrict__ mix, const float* __restrict__ noi,
        float* __restrict__ part) {
    constexpr int TCHUNK = T_ / TSPLIT;
    constexpr int PIPE = 4;
    static_assert(TCHUNK > PIPE, "pipeline deeper than chunk");

    int f = blockIdx.x * 64 + threadIdx.x;
    if (f >= F_) return;
    int n = blockIdx.y;
    int z = blockIdx.z;
    int m = z & 1;
    int chunk = z >> 1;
    const float* src = m ? mix : noi;
    const float* pt = src + (size_t)n * NSTR_ + f + (size_t)(chunk * TCHUNK) * F_;

    float reB[PIPE][C_], imB[PIPE][C_];
    // Prologue: fill PIPE slots (64 loads issued before any consumption).
#pragma unroll
    for (int s = 0; s < PIPE; ++s) {
        const float* pn = pt + (size_t)s * F_;
#pragma unroll
        for (int c = 0; c < C_; ++c) {
            reB[s][c] = pn[(size_t)c * TF_];
            imB[s][c] = pn[(size_t)c * TF_ + CTF_];
        }
    }

    float accr[NPAIR_], acci[NPAIR_];
#pragma unroll
    for (int p = 0; p < NPAIR_; ++p) { accr[p] = 0.f; acci[p] = 0.f; }

#pragma unroll
    for (int tt = 0; tt < TCHUNK; ++tt) {
        const int s = tt % PIPE;
        // Consume slot s into locals (register rename), then refill early so
        // the next loads issue before the FMA block.
        float re[C_], im[C_];
#pragma unroll
        for (int c = 0; c < C_; ++c) { re[c] = reB[s][c]; im[c] = imB[s][c]; }

        if (tt + PIPE < TCHUNK) {
            const float* pn = pt + (size_t)(tt + PIPE) * F_;
#pragma unroll
            for (int c = 0; c < C_; ++c) {
                reB[s][c] = pn[(size_t)c * TF_];
                imB[s][c] = pn[(size_t)c * TF_ + CTF_];
            }
        }

        int p = 0;
#pragma unroll
        for (int c = 0; c < C_; ++c) {
#pragma unroll
            for (int d = 0; d <= c; ++d, ++p) {
                accr[p] += re[c]*re[d] + im[c]*im[d];
                acci[p] += im[c]*re[d] - re[c]*im[d];
            }
        }
    }

    float* out = part + (size_t)((m * TSPLIT + chunk) * 72) * NF_ + n * F_ + f;
#pragma unroll
    for (int p = 0; p < NPAIR_; ++p) {
        out[(size_t)(2*p)   * NF_] = accr[p];
        out[(size_t)(2*p+1) * NF_] = acci[p];
    }
}

// ---------------------------------------------------------------------------
// Phase B1: reduce the chunks into the chunk-0 slot, float4-vectorized.
// One thread per (m, q, idx4): 2*72*514 = 74016 threads. All strides are
// multiples of NF_ floats = 8224 B (16B-aligned), idx4*16 B aligned.
// ---------------------------------------------------------------------------
__global__ __launch_bounds__(256) void reduce_cov(float* __restrict__ part, int tsplit) {
    int flat = blockIdx.x * 256 + threadIdx.x;
    constexpr int NQ4 = NF_ / 4;   // 514
    if (flat >= 2 * 72 * NQ4) return;
    int idx4 = flat % NQ4;
    int z = flat / NQ4;          // z = m*72 + q
    int m = z / 72;
    int q = z % 72;
    const float4* p4 = (const float4*)(part) + ((size_t)((m * tsplit) * 72 + q) * NF_) / 4 + idx4;
    float4 s = {0.f, 0.f, 0.f, 0.f};
    for (int ch = 0; ch < tsplit; ++ch) {
        float4 v = p4[(size_t)(ch * 72) * NF_ / 4];
        s.x += v.x; s.y += v.y; s.z += v.z; s.w += v.w;
    }
    *(float4*)((float*)part + (size_t)((m * tsplit) * 72 + q) * NF_ + idx4 * 4) = s;
}

// ---------------------------------------------------------------------------
// Phase B2: streaming solve. One thread per (n,f). yBase = tsplit*72*NF_.
// ---------------------------------------------------------------------------
__global__ __launch_bounds__(64, 1) void solve_w(
        const float* __restrict__ part, float* __restrict__ W, size_t yBase) {
    int idx = blockIdx.x * 64 + threadIdx.x;  // idx = n*F + f
    if (idx >= NF_) return;

    const float* pv = part + idx;            // m=0, chunk 0
    const float* py = part + yBase + idx;    // m=1, chunk 0

    // Build M = phi_v/T + LOAD*(1+i)*I directly from loads.
    cx M[64];
#pragma unroll
    for (int c = 0; c < 8; ++c) {
#pragma unroll
        for (int d = 0; d <= c; ++d) {
            int p = c*(c+1)/2 + d;
            cx val = { pv[(size_t)(2*p) * NF_] * INV_T_,
                       pv[(size_t)(2*p+1) * NF_] * INV_T_ };
            if (d == c) { val.r += LOADC_; val.i += LOADC_; }
            M[c*8 + d] = val;
            if (d < c) M[d*8 + c] = cconj(val);
        }
    }

    // In-place Gauss-Jordan inverse, no pivoting (diagonally dominant).
#pragma unroll
    for (int k = 0; k < 8; ++k) {
        cx p = cinv(M[k*8 + k]);
        M[k*8 + k] = p;
#pragma unroll
        for (int j = 0; j < 8; ++j) {
            if (j != k) M[k*8 + j] = cmul(M[k*8 + j], p);
        }
#pragma unroll
        for (int i = 0; i < 8; ++i) {
            if (i == k) continue;
            cx fkt = M[i*8 + k];
#pragma unroll
            for (int j = 0; j < 8; ++j) {
                if (j != k) M[i*8 + j] = csub(M[i*8 + j], cmul(fkt, M[k*8 + j]));
            }
            cx t = cmul(fkt, p);
            M[i*8 + k] = { -t.r, -t.i };
        }
    }

    // Stream the 36 stored y-pairs: yv = phi_y[a][b] (a >= b), scaled by 1/T.
    cx tr = {0.f, 0.f};
    cx g0[8];
#pragma unroll
    for (int c = 0; c < 8; ++c) g0[c] = (cx){0.f, 0.f};

#pragma unroll
    for (int a = 0; a < 8; ++a) {
#pragma unroll
        for (int b = 0; b <= a; ++b) {
            int p = a*(a+1)/2 + b;
            cx yv = { py[(size_t)(2*p) * NF_] * INV_T_,
                      py[(size_t)(2*p+1) * NF_] * INV_T_ };
            tr = cmadd(tr, M[b*8 + a], yv);
            if (a != b) tr = cmadd(tr, M[a*8 + b], cconj(yv));
            if (b == 0) {
#pragma unroll
                for (int i = 0; i < 8; ++i) g0[i] = cmadd(g0[i], M[i*8 + a], yv);
            }
        }
    }

    cx l = { tr.r - 8.0f, tr.i - 8.0f };
    float iden = 1.0f / (l.r*l.r + l.i*l.i);

    float* w = W + (size_t)idx * 16;
#pragma unroll
    for (int c = 0; c < 8; ++c) {
        cx ge = g0[c];
        if (c == 0) ge.r -= 1.0f;
        // W = conj(H) = conj(ge) * l / |l|^2
        w[2*c]     = (ge.r*l.r + ge.i*l.i) * iden;
        w[2*c + 1] = (ge.r*l.i - ge.i*l.r) * iden;
    }
}

// ---------------------------------------------------------------------------
// Phase C: beamform. grid (ceil(TF/256), N), block 256. Thread owns flat j=t*F+f.
// ---------------------------------------------------------------------------
__global__ __launch_bounds__(256) void beamform(
        const float* __restrict__ mix, const float* __restrict__ W,
        float* __restrict__ out) {
    int n = blockIdx.y;
    int j = blockIdx.x * 256 + threadIdx.x;
    if (j >= TF_) return;
    int f = j % F_;

    const float4* w4 = (const float4*)(W + (size_t)(n * F_ + f) * 16);
    float4 q0 = w4[0], q1 = w4[1], q2 = w4[2], q3 = w4[3];
    float wv[16] = { q0.x, q0.y, q0.z, q0.w,
                     q1.x, q1.y, q1.z, q1.w,
                     q2.x, q2.y, q2.z, q2.w,
                     q3.x, q3.y, q3.z, q3.w };

    const float* base = mix + (size_t)n * NSTR_ + j;
    float xr = 0.f, xi = 0.f;
#pragma unroll
    for (int c = 0; c < C_; ++c) {
        float yr = base[(size_t)c * TF_];
        float yi = base[(size_t)c * TF_ + CTF_];
        float wr = wv[2*c], wi = wv[2*c + 1];
        xr += wr*yr - wi*yi;
        xi += wr*yi + wi*yr;
    }
    float* op = out + (size_t)n * (2 * TF_);
    op[j]       = xr;
    op[TF_ + j] = xi;
}

extern "C" void kernel_launch(void* const* d_in, const int* in_sizes, int n_in,
                              void* d_out, int out_size, void* d_ws, size_t ws_size,
                              hipStream_t stream) {
    const float* mix = (const float*)d_in[0];
    // d_in[1] = target, unused by the reference
    const float* noi = (const float*)d_in[2];

    // TSPLIT=25 needs 2*25*72*NF + 16*NF floats of scratch (~29.7 MB).
    const size_t need25 = ((size_t)2 * 25 * 72 * NF_ + (size_t)16 * NF_) * 4;
    float* part = (float*)d_ws;
    int tsplit;
    if (ws_size >= need25) {
        tsplit = 25;   // TCHUNK=24, PIPE=4: 2000 waves, ~7.8/CU
        cov_partial<25><<<dim3(5, N_, 2 * 25), 64, 0, stream>>>(mix, noi, part);
    } else {
        tsplit = 15;   // fallback, TCHUNK=40
        cov_partial<15><<<dim3(5, N_, 2 * 15), 64, 0, stream>>>(mix, noi, part);
    }
    float* W = part + (size_t)2 * tsplit * 72 * NF_;

    reduce_cov<<<dim3((2 * 72 * (NF_ / 4) + 255) / 256), 256, 0, stream>>>(part, tsplit);
    solve_w<<<dim3((NF_ + 63) / 64), 64, 0, stream>>>(part, W, (size_t)tsplit * 72 * NF_);
    beamform<<<dim3((TF_ + 255) / 256, N_), 256, 0, stream>>>(mix, W, (float*)d_out);
}